// Round 4
// baseline (2838.473 us; speedup 1.0000x reference)
//
#include <hip/hip_runtime.h>
#include <cmath>

#define B_  128
#define T_  512
#define E_  128
#define H_  128
#define G4  512   // 4*H
#define K_  9

// ---------------------------------------------------------------------------
// Kernel 1: input projection GEMM with fused embedding gather.
// proj[b][tc][n] = sum_k embed[sent[b,t]][k] * W_dir[n'][k] + (bih+bhh)[n']
//   cols [0,512)  -> forward  dir, t = t0f + tc
//   cols [512,1024)-> backward dir, t = t0b + tc,  t0b = T - t0f - Tc
//
// R4 rewrite: 128(M) x 128(N) tile, K staged 32 at a time, double-buffered
// LDS, 256 threads, 8x8 micro-tile (2x2 blocks of 4x4 at +64 offsets).
//   Old 64x64/4x4 version was DS-pipe bound (2 ds_read_b128 per 16 FMA,
//   ~3:1 DS:VALU per CU) at ~44 TF. New shape: 4 ds_read_b128 per 64 FMA,
//   fragment addresses mg*4 / mg*4+64 -> only 2-way bank alias (free).
//   Staging: global->reg issued before compute slice, reg->LDS after
//   (latency hidden under 2048 FMAs). LDS 64KB -> 2 blocks/CU.
// ---------------------------------------------------------------------------
__global__ __launch_bounds__(256, 2)
void proj_gemm(const int* __restrict__ sent, const float* __restrict__ embed,
               const float* __restrict__ Wf, const float* __restrict__ Wb,
               const float* __restrict__ bif, const float* __restrict__ bhf,
               const float* __restrict__ bib, const float* __restrict__ bhb,
               float* __restrict__ proj, int t0f, int Tc)
{
  __shared__ __align__(16) float Al[2][32][128];  // [buf][k][m]  32KB
  __shared__ __align__(16) float Bl[2][32][128];  // [buf][k][n]  32KB
  const int tid   = threadIdx.x;           // 0..255
  const int ntile = blockIdx.x;            // 0..7  (4 per direction)
  const int mtile = blockIdx.y;            // 0..B*Tc/128-1
  const int dir   = ntile >> 2;
  const int n0    = (ntile & 3) << 7;      // within-dir col offset 0..384
  const int t0    = dir ? (T_ - t0f - Tc) : t0f;
  const float* __restrict__ W = dir ? Wb : Wf;

  // staging role: 2 threads per row, each covers 16 of the 32 stage-k's
  const int row = tid & 127;
  const int kh  = (tid >> 7) << 4;         // 0 or 16
  const int mrow0 = mtile * 128 + row;     // global M row this thread stages
  const int b   = mrow0 / Tc;
  const int tc  = mrow0 - b * Tc;
  const int vid = sent[b * T_ + t0 + tc];
  const float* __restrict__ arow = embed + (size_t)vid * E_ + kh;
  const float* __restrict__ brow = W + (size_t)(n0 + row) * E_ + kh;

  float4 va[4], vb[4];
#pragma unroll
  for (int q = 0; q < 4; ++q) {            // stage 0 loads
    va[q] = *(const float4*)(arow + q * 4);
    vb[q] = *(const float4*)(brow + q * 4);
  }
#pragma unroll
  for (int q = 0; q < 4; ++q) {            // stage 0 LDS writes (lane-consec)
    const int k = kh + q * 4;
    Al[0][k + 0][row] = va[q].x; Al[0][k + 1][row] = va[q].y;
    Al[0][k + 2][row] = va[q].z; Al[0][k + 3][row] = va[q].w;
    Bl[0][k + 0][row] = vb[q].x; Bl[0][k + 1][row] = vb[q].y;
    Bl[0][k + 2][row] = vb[q].z; Bl[0][k + 3][row] = vb[q].w;
  }

  const int mg = tid & 15, ng = tid >> 4;  // 16x16 thread grid
  float acc[8][8] = {};

  for (int s = 0; s < 4; ++s) {
    __syncthreads();                       // buf[s&1] ready; prev readers done
    if (s < 3) {
      const int kb = (s + 1) * 32;
#pragma unroll
      for (int q = 0; q < 4; ++q) {
        va[q] = *(const float4*)(arow + kb + q * 4);
        vb[q] = *(const float4*)(brow + kb + q * 4);
      }
    }
    const int bs = s & 1;
#pragma unroll
    for (int k = 0; k < 32; ++k) {
      float4 a0 = *(const float4*)&Al[bs][k][mg * 4];
      float4 a1 = *(const float4*)&Al[bs][k][64 + mg * 4];
      float4 b0 = *(const float4*)&Bl[bs][k][ng * 4];
      float4 b1 = *(const float4*)&Bl[bs][k][64 + ng * 4];
      float av[8] = {a0.x, a0.y, a0.z, a0.w, a1.x, a1.y, a1.z, a1.w};
      float bv[8] = {b0.x, b0.y, b0.z, b0.w, b1.x, b1.y, b1.z, b1.w};
#pragma unroll
      for (int i = 0; i < 8; ++i)
#pragma unroll
        for (int j = 0; j < 8; ++j) acc[i][j] += av[i] * bv[j];
    }
    if (s < 3) {
      const int nb = (s + 1) & 1;
#pragma unroll
      for (int q = 0; q < 4; ++q) {
        const int k = kh + q * 4;
        Al[nb][k + 0][row] = va[q].x; Al[nb][k + 1][row] = va[q].y;
        Al[nb][k + 2][row] = va[q].z; Al[nb][k + 3][row] = va[q].w;
        Bl[nb][k + 0][row] = vb[q].x; Bl[nb][k + 1][row] = vb[q].y;
        Bl[nb][k + 2][row] = vb[q].z; Bl[nb][k + 3][row] = vb[q].w;
      }
    }
  }

  const float* bi = dir ? bib : bif;
  const float* bh = dir ? bhb : bhf;
  float bias[8];
#pragma unroll
  for (int cj = 0; cj < 8; ++cj) {
    const int col = n0 + (cj >> 2) * 64 + ng * 4 + (cj & 3);
    bias[cj] = bi[col] + bh[col];
  }
#pragma unroll
  for (int ri = 0; ri < 8; ++ri) {
    const int mrow = mtile * 128 + (ri >> 2) * 64 + mg * 4 + (ri & 3);
    float* prow = proj + (size_t)mrow * 1024 + dir * G4 + n0;
    float4 o0, o1;
    o0.x = acc[ri][0] + bias[0]; o0.y = acc[ri][1] + bias[1];
    o0.z = acc[ri][2] + bias[2]; o0.w = acc[ri][3] + bias[3];
    o1.x = acc[ri][4] + bias[4]; o1.y = acc[ri][5] + bias[5];
    o1.z = acc[ri][6] + bias[6]; o1.w = acc[ri][7] + bias[7];
    *(float4*)&prow[ng * 4]      = o0;
    *(float4*)&prow[64 + ng * 4] = o1;
  }
}

// ---------------------------------------------------------------------------
// Kernel 2: LSTM recurrence, one block per (direction, batch element).
// 512 threads: thread g owns gate row g (Whh[g][:], AGPR/VGPR-resident).
// h lives in LDS (broadcast reads); c in registers of threads 0..127.
// Packed-sequence semantics: state frozen + output zeroed where t >= len.
// (R2 version restored — R3's pair-split regressed: LDS bank conflicts +
//  shuffle traffic; weights live in AGPRs either way, ~266us/chunk.)
// ---------------------------------------------------------------------------
__global__ __launch_bounds__(512, 1)
void lstm_chunk(const float* __restrict__ proj,
                const float* __restrict__ Whf, const float* __restrict__ Whb,
                const int* __restrict__ lengths,
                float* __restrict__ hs,
                float* __restrict__ sh, float* __restrict__ sc,
                int t0f, int Tc, int first)
{
  const int dir = blockIdx.x;
  const int b   = blockIdx.y;
  const int tid = threadIdx.x;
  const float* __restrict__ Whh = dir ? Whb : Whf;
  __shared__ __align__(16) float h_lds[H_];
  __shared__ float gates[G4];

  float w[128];
  {
    const float* wr = Whh + (size_t)tid * H_;
#pragma unroll
    for (int k = 0; k < 128; k += 4) {
      float4 v = *(const float4*)(wr + k);
      w[k] = v.x; w[k + 1] = v.y; w[k + 2] = v.z; w[k + 3] = v.w;
    }
  }
  // Pin the weight row on-chip (prevents rematerialized global loads).
#pragma unroll
  for (int k = 0; k < 128; ++k) asm volatile("" : "+v"(w[k]));

  const int len = lengths[b];
  const int t0  = dir ? (T_ - t0f - Tc) : t0f;
  float c = 0.f;
  if (tid < H_) {
    if (first) {
      h_lds[tid] = 0.f;
    } else {
      h_lds[tid] = sh[(dir * B_ + b) * H_ + tid];
      c          = sc[(dir * B_ + b) * H_ + tid];
    }
  }
  __syncthreads();

  const float* projp = proj + (size_t)b * Tc * 1024 + dir * G4 + tid;
  float pv = projp[(size_t)(dir ? (Tc - 1) : 0) * 1024];
  for (int s = 0; s < Tc; ++s) {
    const int tc = dir ? (Tc - 1 - s) : s;   // backward scans t descending
    const int t  = t0 + tc;
    float nv = 0.f;
    if (s + 1 < Tc) {
      const int tcn = dir ? (Tc - 2 - s) : (s + 1);
      nv = projp[(size_t)tcn * 1024];
    }
    float a0 = 0.f, a1 = 0.f, a2 = 0.f, a3 = 0.f;
#pragma unroll
    for (int k4 = 0; k4 < 32; ++k4) {
      float4 h4 = *(const float4*)&h_lds[k4 * 4];
      a0 += w[4 * k4 + 0] * h4.x; a1 += w[4 * k4 + 1] * h4.y;
      a2 += w[4 * k4 + 2] * h4.z; a3 += w[4 * k4 + 3] * h4.w;
    }
    float acc = pv + (a0 + a1) + (a2 + a3);
    const int blk = tid >> 7;                // 0:i 1:f 2:g 3:o (torch order)
    gates[tid] = (blk == 2) ? tanhf(acc) : 1.f / (1.f + expf(-acc));
    __syncthreads();
    if (tid < H_) {
      float gi = gates[tid], gf = gates[tid + 128];
      float gg = gates[tid + 256], go = gates[tid + 384];
      float cn = gf * c + gi * gg;
      float hn = go * tanhf(cn);
      bool  m  = (t < len);
      float hold = h_lds[tid];
      c = m ? cn : c;
      h_lds[tid] = m ? hn : hold;
      hs[(size_t)(b * T_ + t) * 256 + dir * H_ + tid] = m ? hn : 0.f;
    }
    __syncthreads();
    pv = nv;
  }
  if (tid < H_) {
    sh[(dir * B_ + b) * H_ + tid] = h_lds[tid];
    sc[(dir * B_ + b) * H_ + tid] = c;
  }
}

// ---------------------------------------------------------------------------
// Kernel 3: emissions em[m][k] = hs[m][:] . W_out[k][:] + b_out[k]
// ---------------------------------------------------------------------------
__global__ __launch_bounds__(256)
void emis_kernel(const float* __restrict__ hs, const float* __restrict__ Wout,
                 const float* __restrict__ bout, float* __restrict__ em)
{
  __shared__ __align__(16) float Wl[K_ * 256];
  const int tid = threadIdx.x;
  for (int i = tid; i < K_ * 256; i += 256) Wl[i] = Wout[i];
  __syncthreads();
  const int m = blockIdx.x * 256 + tid;
  const float* h = hs + (size_t)m * 256;
  float acc[K_] = {};
#pragma unroll 4
  for (int kk = 0; kk < 64; ++kk) {
    float4 h4 = *(const float4*)(h + kk * 4);
#pragma unroll
    for (int k9 = 0; k9 < K_; ++k9) {
      float4 w4 = *(const float4*)&Wl[k9 * 256 + kk * 4];
      acc[k9] += h4.x * w4.x + h4.y * w4.y + h4.z * w4.z + h4.w * w4.w;
    }
  }
#pragma unroll
  for (int k9 = 0; k9 < K_; ++k9) em[(size_t)m * K_ + k9] = acc[k9] + bout[k9];
}

// ---------------------------------------------------------------------------
// Kernel 4: Viterbi decode, one 64-lane wave per batch element.
// Lane k (<9) carries score[k]; shuffles broadcast the score vector.
// Backpointers as uint8 in LDS; padded positions written 0.
// ---------------------------------------------------------------------------
__global__ __launch_bounds__(64)
void viterbi_kernel(const float* __restrict__ em, const int* __restrict__ lengths,
                    const float* __restrict__ st, const float* __restrict__ en,
                    const float* __restrict__ trans, int* __restrict__ tags)
{
  const int b    = blockIdx.x;
  const int lane = threadIdx.x;
  __shared__ unsigned char hist[(T_ - 1) * 16];
  const int len = lengths[b];
  float tr[K_];
#pragma unroll
  for (int j = 0; j < K_; ++j) tr[j] = (lane < K_) ? trans[j * K_ + lane] : 0.f;
  float s = (lane < K_) ? st[lane] + em[(size_t)(b * T_) * K_ + lane] : -1e30f;
  for (int t = 1; t < len; ++t) {
    float best = -1e30f; int bj = 0;
#pragma unroll
    for (int j = 0; j < K_; ++j) {
      float v = __shfl(s, j) + tr[j];
      if (v > best) { best = v; bj = j; }    // strict > == first-max (argmax)
    }
    if (lane < K_) {
      s = best + em[(size_t)(b * T_ + t) * K_ + lane];
      hist[(t - 1) * 16 + lane] = (unsigned char)bj;
    }
  }
  float fs = (lane < K_) ? s + en[lane] : -1e30f;
  float best = -1e30f; int last = 0;
#pragma unroll
  for (int j = 0; j < K_; ++j) {
    float v = __shfl(fs, j);
    if (v > best) { best = v; last = j; }
  }
  __syncthreads();                            // hist visible to lane 0
  if (lane == 0) {
    int tag = last;
    tags[b * T_ + len - 1] = tag;
    for (int t = len - 2; t >= 0; --t) {
      tag = hist[t * 16 + tag];
      tags[b * T_ + t] = tag;
    }
  }
  for (int t = len + lane; t < T_; t += 64) tags[b * T_ + t] = 0;
}

// ---------------------------------------------------------------------------
extern "C" void kernel_launch(void* const* d_in, const int* in_sizes, int n_in,
                              void* d_out, int out_size, void* d_ws, size_t ws_size,
                              hipStream_t stream)
{
  const int*   sent  = (const int*)d_in[0];
  const int*   lens  = (const int*)d_in[1];
  const float* embed = (const float*)d_in[2];
  const float* Wif   = (const float*)d_in[3];
  const float* Whf   = (const float*)d_in[4];
  const float* bif   = (const float*)d_in[5];
  const float* bhf   = (const float*)d_in[6];
  const float* Wib   = (const float*)d_in[7];
  const float* Whb   = (const float*)d_in[8];
  const float* bib   = (const float*)d_in[9];
  const float* bhb   = (const float*)d_in[10];
  const float* Wout  = (const float*)d_in[11];
  const float* bout  = (const float*)d_in[12];
  const float* stt   = (const float*)d_in[13];
  const float* ent   = (const float*)d_in[14];
  const float* trans = (const float*)d_in[15];
  int* tags = (int*)d_out;

  // workspace layout (floats): hs | em | state_h | state_c | proj(chunked)
  float* ws   = (float*)d_ws;
  float* hs   = ws;                                  // B*T*256   (67.1 MB)
  float* em   = hs + (size_t)B_ * T_ * 256;          // B*T*9     ( 2.4 MB)
  float* sh   = em + (size_t)B_ * T_ * K_;           // 2*B*H carry h
  float* sc   = sh + (size_t)2 * B_ * H_;            // 2*B*H carry c
  float* proj = sc + (size_t)2 * B_ * H_;
  const size_t fixed_bytes = (size_t)(proj - ws) * sizeof(float);

  // largest time-chunk whose proj buffer fits (floor 128: GEMM M-tile = 128)
  int Tc = 512;
  while (Tc > 128 && fixed_bytes + (size_t)B_ * Tc * 1024 * sizeof(float) > ws_size)
    Tc >>= 1;

  const int nch = T_ / Tc;
  for (int c2 = 0; c2 < nch; ++c2) {
    const int t0f = c2 * Tc;
    dim3 g1(8, (B_ * Tc) >> 7);
    hipLaunchKernelGGL(proj_gemm, g1, dim3(256), 0, stream,
                       sent, embed, Wif, Wib, bif, bhf, bib, bhb, proj, t0f, Tc);
    dim3 g2(2, B_);
    hipLaunchKernelGGL(lstm_chunk, g2, dim3(512), 0, stream,
                       proj, Whf, Whb, lens, hs, sh, sc, t0f, Tc, (int)(c2 == 0));
  }
  hipLaunchKernelGGL(emis_kernel, dim3((B_ * T_) / 256), dim3(256), 0, stream,
                     hs, Wout, bout, em);
  hipLaunchKernelGGL(viterbi_kernel, dim3(B_), dim3(64), 0, stream,
                     em, lens, stt, ent, trans, tags);
}

// Round 5
// 1059.226 us; speedup vs baseline: 2.6798x; 2.6798x over previous
//
#include <hip/hip_runtime.h>
#include <cmath>

#define B_  128
#define T_  512
#define E_  128
#define H_  128
#define G4  512   // 4*H
#define K_  9

// ---------------------------------------------------------------------------
// Kernel 1: input projection GEMM with fused embedding gather.
// proj[b][tc][n] = sum_k embed[sent[b,t]][k] * W_dir[n'][k] + (bih+bhh)[n']
//   cols [0,512)  -> forward  dir, t = t0f + tc
//   cols [512,1024)-> backward dir, t = t0b + tc,  t0b = T - t0f - Tc
//
// R5: 128(M) x 128(N) tile, 256 threads, 8x8 micro-tile, K in two 64-slices,
// SINGLE-buffered LDS (64KB -> 2 blocks/CU).
//   R4's double-buffered variant spilled acc to scratch (VALUBusy 0.3%,
//   4.9GB HBM traffic/dispatch = scratch thrash, occupancy 0.9%). This
//   version minimizes live registers: no prefetch regs across the compute
//   loop, no scalar copy arrays (FMAs on float4 components via macros),
//   acc = 16 float4 with static indices. ~115 VGPR peak -> no spill.
//   DS floor: 4 ds_read_b128 / 64 FMA -> ~82us/dispatch.
// ---------------------------------------------------------------------------
#define MT8(L, R, A)                                              \
  L.x += A * B0.x; L.y += A * B0.y; L.z += A * B0.z; L.w += A * B0.w; \
  R.x += A * B1.x; R.y += A * B1.y; R.z += A * B1.z; R.w += A * B1.w;

__global__ __launch_bounds__(256)
void proj_gemm(const int* __restrict__ sent, const float* __restrict__ embed,
               const float* __restrict__ Wf, const float* __restrict__ Wb,
               const float* __restrict__ bif, const float* __restrict__ bhf,
               const float* __restrict__ bib, const float* __restrict__ bhb,
               float* __restrict__ proj, int t0f, int Tc)
{
  __shared__ __align__(16) float Al[64][128];  // [k][m] 32KB
  __shared__ __align__(16) float Bl[64][128];  // [k][n] 32KB
  const int tid   = threadIdx.x;           // 0..255
  const int ntile = blockIdx.x;            // 0..7 (4 col-tiles per direction)
  const int mtile = blockIdx.y;
  const int dir   = ntile >> 2;
  const int n0    = (ntile & 3) << 7;      // within-dir col offset 0..384
  const int t0    = dir ? (T_ - t0f - Tc) : t0f;
  const float* __restrict__ W = dir ? Wb : Wf;

  // staging role: 2 threads per row, each covers 32 of the 64 slice-k's
  const int row   = tid & 127;
  const int kh    = (tid >> 7) << 5;       // 0 or 32
  const int mrow0 = mtile * 128 + row;
  const int b     = mrow0 / Tc;
  const int tc    = mrow0 - b * Tc;
  const int vid   = sent[b * T_ + t0 + tc];
  const float* __restrict__ arow = embed + (size_t)vid * E_ + kh;
  const float* __restrict__ brow = W + (size_t)(n0 + row) * E_ + kh;

  const int mg = tid & 15, ng = tid >> 4;  // 16x16 thread grid
  float4 accL[8] = {}, accR[8] = {};       // rows: mg*4+i / 64+mg*4+i
                                           // cols: n0+ng*4.. / n0+64+ng*4..
  for (int s = 0; s < 2; ++s) {
    if (s) __syncthreads();                // readers of previous slice done
    const int kb = s << 6;
#pragma unroll
    for (int q = 0; q < 8; ++q) {          // stage A slice
      float4 v = *(const float4*)(arow + kb + q * 4);
      const int k = kh + q * 4;
      Al[k + 0][row] = v.x; Al[k + 1][row] = v.y;
      Al[k + 2][row] = v.z; Al[k + 3][row] = v.w;
    }
#pragma unroll
    for (int q = 0; q < 8; ++q) {          // stage B slice
      float4 v = *(const float4*)(brow + kb + q * 4);
      const int k = kh + q * 4;
      Bl[k + 0][row] = v.x; Bl[k + 1][row] = v.y;
      Bl[k + 2][row] = v.z; Bl[k + 3][row] = v.w;
    }
    __syncthreads();
#pragma unroll
    for (int k = 0; k < 64; ++k) {
      float4 A0 = *(const float4*)&Al[k][mg * 4];
      float4 A1 = *(const float4*)&Al[k][64 + mg * 4];
      float4 B0 = *(const float4*)&Bl[k][ng * 4];
      float4 B1 = *(const float4*)&Bl[k][64 + ng * 4];
      MT8(accL[0], accR[0], A0.x)
      MT8(accL[1], accR[1], A0.y)
      MT8(accL[2], accR[2], A0.z)
      MT8(accL[3], accR[3], A0.w)
      MT8(accL[4], accR[4], A1.x)
      MT8(accL[5], accR[5], A1.y)
      MT8(accL[6], accR[6], A1.z)
      MT8(accL[7], accR[7], A1.w)
    }
  }

  const float* bi = dir ? bib : bif;
  const float* bh = dir ? bhb : bhf;
  float4 biasL, biasR;
  biasL.x = bi[n0 + ng * 4 + 0] + bh[n0 + ng * 4 + 0];
  biasL.y = bi[n0 + ng * 4 + 1] + bh[n0 + ng * 4 + 1];
  biasL.z = bi[n0 + ng * 4 + 2] + bh[n0 + ng * 4 + 2];
  biasL.w = bi[n0 + ng * 4 + 3] + bh[n0 + ng * 4 + 3];
  biasR.x = bi[n0 + 64 + ng * 4 + 0] + bh[n0 + 64 + ng * 4 + 0];
  biasR.y = bi[n0 + 64 + ng * 4 + 1] + bh[n0 + 64 + ng * 4 + 1];
  biasR.z = bi[n0 + 64 + ng * 4 + 2] + bh[n0 + 64 + ng * 4 + 2];
  biasR.w = bi[n0 + 64 + ng * 4 + 3] + bh[n0 + 64 + ng * 4 + 3];
#pragma unroll
  for (int i = 0; i < 8; ++i) {
    const int mrow = mtile * 128 + (i >> 2) * 64 + mg * 4 + (i & 3);
    float* prow = proj + (size_t)mrow * 1024 + dir * G4 + n0;
    float4 oL, oR;
    oL.x = accL[i].x + biasL.x; oL.y = accL[i].y + biasL.y;
    oL.z = accL[i].z + biasL.z; oL.w = accL[i].w + biasL.w;
    oR.x = accR[i].x + biasR.x; oR.y = accR[i].y + biasR.y;
    oR.z = accR[i].z + biasR.z; oR.w = accR[i].w + biasR.w;
    *(float4*)&prow[ng * 4]      = oL;
    *(float4*)&prow[64 + ng * 4] = oR;
  }
}

// ---------------------------------------------------------------------------
// Kernel 2: LSTM recurrence, one block per (direction, batch element).
// 512 threads: thread g owns gate row g (Whh[g][:], AGPR/VGPR-resident).
// h lives in LDS (broadcast reads); c in registers of threads 0..127.
// Packed-sequence semantics: state frozen + output zeroed where t >= len.
// (R2 version, measured 266us/chunk — do not touch.)
// ---------------------------------------------------------------------------
__global__ __launch_bounds__(512, 1)
void lstm_chunk(const float* __restrict__ proj,
                const float* __restrict__ Whf, const float* __restrict__ Whb,
                const int* __restrict__ lengths,
                float* __restrict__ hs,
                float* __restrict__ sh, float* __restrict__ sc,
                int t0f, int Tc, int first)
{
  const int dir = blockIdx.x;
  const int b   = blockIdx.y;
  const int tid = threadIdx.x;
  const float* __restrict__ Whh = dir ? Whb : Whf;
  __shared__ __align__(16) float h_lds[H_];
  __shared__ float gates[G4];

  float w[128];
  {
    const float* wr = Whh + (size_t)tid * H_;
#pragma unroll
    for (int k = 0; k < 128; k += 4) {
      float4 v = *(const float4*)(wr + k);
      w[k] = v.x; w[k + 1] = v.y; w[k + 2] = v.z; w[k + 3] = v.w;
    }
  }
  // Pin the weight row on-chip (prevents rematerialized global loads).
#pragma unroll
  for (int k = 0; k < 128; ++k) asm volatile("" : "+v"(w[k]));

  const int len = lengths[b];
  const int t0  = dir ? (T_ - t0f - Tc) : t0f;
  float c = 0.f;
  if (tid < H_) {
    if (first) {
      h_lds[tid] = 0.f;
    } else {
      h_lds[tid] = sh[(dir * B_ + b) * H_ + tid];
      c          = sc[(dir * B_ + b) * H_ + tid];
    }
  }
  __syncthreads();

  const float* projp = proj + (size_t)b * Tc * 1024 + dir * G4 + tid;
  float pv = projp[(size_t)(dir ? (Tc - 1) : 0) * 1024];
  for (int s = 0; s < Tc; ++s) {
    const int tc = dir ? (Tc - 1 - s) : s;   // backward scans t descending
    const int t  = t0 + tc;
    float nv = 0.f;
    if (s + 1 < Tc) {
      const int tcn = dir ? (Tc - 2 - s) : (s + 1);
      nv = projp[(size_t)tcn * 1024];
    }
    float a0 = 0.f, a1 = 0.f, a2 = 0.f, a3 = 0.f;
#pragma unroll
    for (int k4 = 0; k4 < 32; ++k4) {
      float4 h4 = *(const float4*)&h_lds[k4 * 4];
      a0 += w[4 * k4 + 0] * h4.x; a1 += w[4 * k4 + 1] * h4.y;
      a2 += w[4 * k4 + 2] * h4.z; a3 += w[4 * k4 + 3] * h4.w;
    }
    float acc = pv + (a0 + a1) + (a2 + a3);
    const int blk = tid >> 7;                // 0:i 1:f 2:g 3:o (torch order)
    gates[tid] = (blk == 2) ? tanhf(acc) : 1.f / (1.f + expf(-acc));
    __syncthreads();
    if (tid < H_) {
      float gi = gates[tid], gf = gates[tid + 128];
      float gg = gates[tid + 256], go = gates[tid + 384];
      float cn = gf * c + gi * gg;
      float hn = go * tanhf(cn);
      bool  m  = (t < len);
      float hold = h_lds[tid];
      c = m ? cn : c;
      h_lds[tid] = m ? hn : hold;
      hs[(size_t)(b * T_ + t) * 256 + dir * H_ + tid] = m ? hn : 0.f;
    }
    __syncthreads();
    pv = nv;
  }
  if (tid < H_) {
    sh[(dir * B_ + b) * H_ + tid] = h_lds[tid];
    sc[(dir * B_ + b) * H_ + tid] = c;
  }
}

// ---------------------------------------------------------------------------
// Kernel 3: emissions em[m][k] = hs[m][:] . W_out[k][:] + b_out[k]
// ---------------------------------------------------------------------------
__global__ __launch_bounds__(256)
void emis_kernel(const float* __restrict__ hs, const float* __restrict__ Wout,
                 const float* __restrict__ bout, float* __restrict__ em)
{
  __shared__ __align__(16) float Wl[K_ * 256];
  const int tid = threadIdx.x;
  for (int i = tid; i < K_ * 256; i += 256) Wl[i] = Wout[i];
  __syncthreads();
  const int m = blockIdx.x * 256 + tid;
  const float* h = hs + (size_t)m * 256;
  float acc[K_] = {};
#pragma unroll 4
  for (int kk = 0; kk < 64; ++kk) {
    float4 h4 = *(const float4*)(h + kk * 4);
#pragma unroll
    for (int k9 = 0; k9 < K_; ++k9) {
      float4 w4 = *(const float4*)&Wl[k9 * 256 + kk * 4];
      acc[k9] += h4.x * w4.x + h4.y * w4.y + h4.z * w4.z + h4.w * w4.w;
    }
  }
#pragma unroll
  for (int k9 = 0; k9 < K_; ++k9) em[(size_t)m * K_ + k9] = acc[k9] + bout[k9];
}

// ---------------------------------------------------------------------------
// Kernel 4: Viterbi decode, one 64-lane wave per batch element.
// Lane k (<9) carries score[k]; shuffles broadcast the score vector.
// Backpointers as uint8 in LDS; padded positions written 0.
// ---------------------------------------------------------------------------
__global__ __launch_bounds__(64)
void viterbi_kernel(const float* __restrict__ em, const int* __restrict__ lengths,
                    const float* __restrict__ st, const float* __restrict__ en,
                    const float* __restrict__ trans, int* __restrict__ tags)
{
  const int b    = blockIdx.x;
  const int lane = threadIdx.x;
  __shared__ unsigned char hist[(T_ - 1) * 16];
  const int len = lengths[b];
  float tr[K_];
#pragma unroll
  for (int j = 0; j < K_; ++j) tr[j] = (lane < K_) ? trans[j * K_ + lane] : 0.f;
  float s = (lane < K_) ? st[lane] + em[(size_t)(b * T_) * K_ + lane] : -1e30f;
  for (int t = 1; t < len; ++t) {
    float best = -1e30f; int bj = 0;
#pragma unroll
    for (int j = 0; j < K_; ++j) {
      float v = __shfl(s, j) + tr[j];
      if (v > best) { best = v; bj = j; }    // strict > == first-max (argmax)
    }
    if (lane < K_) {
      s = best + em[(size_t)(b * T_ + t) * K_ + lane];
      hist[(t - 1) * 16 + lane] = (unsigned char)bj;
    }
  }
  float fs = (lane < K_) ? s + en[lane] : -1e30f;
  float best = -1e30f; int last = 0;
#pragma unroll
  for (int j = 0; j < K_; ++j) {
    float v = __shfl(fs, j);
    if (v > best) { best = v; last = j; }
  }
  __syncthreads();                            // hist visible to lane 0
  if (lane == 0) {
    int tag = last;
    tags[b * T_ + len - 1] = tag;
    for (int t = len - 2; t >= 0; --t) {
      tag = hist[t * 16 + tag];
      tags[b * T_ + t] = tag;
    }
  }
  for (int t = len + lane; t < T_; t += 64) tags[b * T_ + t] = 0;
}

// ---------------------------------------------------------------------------
extern "C" void kernel_launch(void* const* d_in, const int* in_sizes, int n_in,
                              void* d_out, int out_size, void* d_ws, size_t ws_size,
                              hipStream_t stream)
{
  const int*   sent  = (const int*)d_in[0];
  const int*   lens  = (const int*)d_in[1];
  const float* embed = (const float*)d_in[2];
  const float* Wif   = (const float*)d_in[3];
  const float* Whf   = (const float*)d_in[4];
  const float* bif   = (const float*)d_in[5];
  const float* bhf   = (const float*)d_in[6];
  const float* Wib   = (const float*)d_in[7];
  const float* Whb   = (const float*)d_in[8];
  const float* bib   = (const float*)d_in[9];
  const float* bhb   = (const float*)d_in[10];
  const float* Wout  = (const float*)d_in[11];
  const float* bout  = (const float*)d_in[12];
  const float* stt   = (const float*)d_in[13];
  const float* ent   = (const float*)d_in[14];
  const float* trans = (const float*)d_in[15];
  int* tags = (int*)d_out;

  // workspace layout (floats): hs | em | state_h | state_c | proj(chunked)
  float* ws   = (float*)d_ws;
  float* hs   = ws;                                  // B*T*256   (67.1 MB)
  float* em   = hs + (size_t)B_ * T_ * 256;          // B*T*9     ( 2.4 MB)
  float* sh   = em + (size_t)B_ * T_ * K_;           // 2*B*H carry h
  float* sc   = sh + (size_t)2 * B_ * H_;            // 2*B*H carry c
  float* proj = sc + (size_t)2 * B_ * H_;
  const size_t fixed_bytes = (size_t)(proj - ws) * sizeof(float);

  // largest time-chunk whose proj buffer fits (floor 128: GEMM M-tile = 128)
  int Tc = 512;
  while (Tc > 128 && fixed_bytes + (size_t)B_ * Tc * 1024 * sizeof(float) > ws_size)
    Tc >>= 1;

  const int nch = T_ / Tc;
  for (int c2 = 0; c2 < nch; ++c2) {
    const int t0f = c2 * Tc;
    dim3 g1(8, (B_ * Tc) >> 7);
    hipLaunchKernelGGL(proj_gemm, g1, dim3(256), 0, stream,
                       sent, embed, Wif, Wib, bif, bhf, bib, bhb, proj, t0f, Tc);
    dim3 g2(2, B_);
    hipLaunchKernelGGL(lstm_chunk, g2, dim3(512), 0, stream,
                       proj, Whf, Whb, lens, hs, sh, sc, t0f, Tc, (int)(c2 == 0));
  }
  hipLaunchKernelGGL(emis_kernel, dim3((B_ * T_) / 256), dim3(256), 0, stream,
                     hs, Wout, bout, em);
  hipLaunchKernelGGL(viterbi_kernel, dim3(B_), dim3(64), 0, stream,
                     em, lens, stt, ent, trans, tags);
}

// Round 6
// 992.801 us; speedup vs baseline: 2.8591x; 1.0669x over previous
//
#include <hip/hip_runtime.h>
#include <cmath>

#define B_  128
#define T_  512
#define E_  128
#define H_  128
#define G4  512   // 4*H
#define K_  9
#define SB  16    // lstm hs-flush batch (rolling h history depth)

// ---------------------------------------------------------------------------
// Kernel 1: input projection GEMM with fused embedding gather.
// proj[b][tc][n] = sum_k embed[sent[b,t]][k] * W_dir[n'][k] + (bih+bhh)[n']
//   n in [0,512)  -> forward  dir, t = t0f + tc
//   n in [512,1024)-> backward dir, t = t0b + tc,  t0b = T - t0f - Tc
// Tile: 64(M) x 64(N) x 128(K, full), 256 threads, 4x4 micro-tile.
// (R0 version restored: R4 dbuf spilled, R5 single-buf 128x128 was slower
//  (~240us vs ~195us) — staging latency exposed at 2 blocks/CU.)
// ---------------------------------------------------------------------------
__global__ __launch_bounds__(256, 2)
void proj_gemm(const int* __restrict__ sent, const float* __restrict__ embed,
               const float* __restrict__ Wf, const float* __restrict__ Wb,
               const float* __restrict__ bif, const float* __restrict__ bhf,
               const float* __restrict__ bib, const float* __restrict__ bhb,
               float* __restrict__ proj, int t0f, int Tc)
{
  __shared__ __align__(16) float Al[128 * 64];  // [k][m]
  __shared__ __align__(16) float Bl[128 * 64];  // [k][n]
  const int tid   = threadIdx.x;
  const int ntile = blockIdx.x;            // 0..15
  const int mtile = blockIdx.y;
  const int tpb   = Tc >> 6;               // 64-row tiles per batch element
  const int b     = mtile / tpb;
  const int toff  = (mtile - b * tpb) << 6;
  const int dir   = ntile >> 3;
  const int t0    = dir ? (T_ - t0f - Tc) : t0f;
  const float* __restrict__ W = dir ? Wb : Wf;
  const int n0 = (ntile & 7) << 6;         // row offset inside W (0..448)

  // ---- stage A (gathered embed rows) and B (weight rows), k-major in LDS
  {
    const int r  = tid & 63;
    const int kc = tid >> 6;               // 0..3, each covers 32 k's
    const int t  = t0 + toff + r;
    const int vid = sent[b * T_ + t];
    const float* arow = embed + (size_t)vid * E_ + kc * 32;
    const float* brow = W + (size_t)(n0 + r) * E_ + kc * 32;
#pragma unroll
    for (int q = 0; q < 8; ++q) {
      float4 av = *(const float4*)(arow + q * 4);
      float4 bv = *(const float4*)(brow + q * 4);
      int k0 = kc * 32 + q * 4;
      Al[(k0 + 0) * 64 + r] = av.x; Al[(k0 + 1) * 64 + r] = av.y;
      Al[(k0 + 2) * 64 + r] = av.z; Al[(k0 + 3) * 64 + r] = av.w;
      Bl[(k0 + 0) * 64 + r] = bv.x; Bl[(k0 + 1) * 64 + r] = bv.y;
      Bl[(k0 + 2) * 64 + r] = bv.z; Bl[(k0 + 3) * 64 + r] = bv.w;
    }
  }
  __syncthreads();

  const int mg = tid & 15, ng = tid >> 4;
  float acc[4][4] = {};
#pragma unroll 8
  for (int k = 0; k < 128; ++k) {
    float4 a  = *(const float4*)&Al[k * 64 + mg * 4];
    float4 bb = *(const float4*)&Bl[k * 64 + ng * 4];
    acc[0][0] += a.x * bb.x; acc[0][1] += a.x * bb.y; acc[0][2] += a.x * bb.z; acc[0][3] += a.x * bb.w;
    acc[1][0] += a.y * bb.x; acc[1][1] += a.y * bb.y; acc[1][2] += a.y * bb.z; acc[1][3] += a.y * bb.w;
    acc[2][0] += a.z * bb.x; acc[2][1] += a.z * bb.y; acc[2][2] += a.z * bb.z; acc[2][3] += a.z * bb.w;
    acc[3][0] += a.w * bb.x; acc[3][1] += a.w * bb.y; acc[3][2] += a.w * bb.z; acc[3][3] += a.w * bb.w;
  }

  const float* bi = dir ? bib : bif;
  const float* bh = dir ? bhb : bhf;
  const int nl = ng * 4;
  float4 bias;
  bias.x = bi[n0 + nl + 0] + bh[n0 + nl + 0];
  bias.y = bi[n0 + nl + 1] + bh[n0 + nl + 1];
  bias.z = bi[n0 + nl + 2] + bh[n0 + nl + 2];
  bias.w = bi[n0 + nl + 3] + bh[n0 + nl + 3];
#pragma unroll
  for (int i = 0; i < 4; ++i) {
    const int tloc = toff + mg * 4 + i;
    float4 o;
    o.x = acc[i][0] + bias.x; o.y = acc[i][1] + bias.y;
    o.z = acc[i][2] + bias.z; o.w = acc[i][3] + bias.w;
    *(float4*)&proj[((size_t)(b * Tc + tloc)) * 1024 + dir * G4 + n0 + nl] = o;
  }
}

// ---------------------------------------------------------------------------
// Kernel 2: LSTM recurrence, one block per (direction, batch element).
// 512 threads: thread g owns gate row g (Whh[g][:], on-chip resident).
// Packed-sequence semantics: state frozen + output zeroed where t >= len.
//
// R6 change: rolling 16-step h history in LDS + batched hs flush.
//   R2 stored hs to global EVERY step right before __syncthreads(); the
//   compiler's mandatory s_waitcnt vmcnt(0) before s_barrier exposed the
//   full HBM store-ack latency (~300-600cy) on all 256 steps. Now h goes
//   to h_hist[s&15][:] (also removes the h_lds WAR hazard) and all 512
//   threads flush 16 steps of output every 16th step; the drain overlaps
//   the next matvec and is paid 16x less often. Masking (t<len ? h : 0)
//   applied at flush — frozen-state rows re-masked to 0, identical to
//   the per-step masked store.
// ---------------------------------------------------------------------------
__global__ __launch_bounds__(512, 1)
void lstm_chunk(const float* __restrict__ proj,
                const float* __restrict__ Whf, const float* __restrict__ Whb,
                const int* __restrict__ lengths,
                float* __restrict__ hs,
                float* __restrict__ sh, float* __restrict__ sc,
                int t0f, int Tc, int first)
{
  const int dir = blockIdx.x;
  const int b   = blockIdx.y;
  const int tid = threadIdx.x;
  const float* __restrict__ Whh = dir ? Whb : Whf;
  __shared__ __align__(16) float h_hist[SB][H_];   // rolling h history
  __shared__ float gates[G4];

  float w[128];
  {
    const float* wr = Whh + (size_t)tid * H_;
#pragma unroll
    for (int k = 0; k < 128; k += 4) {
      float4 v = *(const float4*)(wr + k);
      w[k] = v.x; w[k + 1] = v.y; w[k + 2] = v.z; w[k + 3] = v.w;
    }
  }
  // Pin the weight row on-chip (prevents rematerialized global loads).
#pragma unroll
  for (int k = 0; k < 128; ++k) asm volatile("" : "+v"(w[k]));

  const int len = lengths[b];
  const int t0  = dir ? (T_ - t0f - Tc) : t0f;
  float c = 0.f;
  if (tid < H_) {
    float h0 = 0.f;
    if (!first) {
      h0 = sh[(dir * B_ + b) * H_ + tid];
      c  = sc[(dir * B_ + b) * H_ + tid];
    }
    h_hist[SB - 1][tid] = h0;        // slot read by step 0's matvec
  }
  __syncthreads();

  const float* projp = proj + (size_t)b * Tc * 1024 + dir * G4 + tid;
  float pv = projp[(size_t)(dir ? (Tc - 1) : 0) * 1024];
  for (int s = 0; s < Tc; ++s) {
    float nv = 0.f;
    if (s + 1 < Tc) {
      const int tcn = dir ? (Tc - 2 - s) : (s + 1);
      nv = projp[(size_t)tcn * 1024];
    }
    const float* hp = h_hist[(s + SB - 1) & (SB - 1)];  // h_{s-1}
    float a0 = 0.f, a1 = 0.f, a2 = 0.f, a3 = 0.f;
#pragma unroll
    for (int k4 = 0; k4 < 32; ++k4) {
      float4 h4 = *(const float4*)&hp[k4 * 4];
      a0 += w[4 * k4 + 0] * h4.x; a1 += w[4 * k4 + 1] * h4.y;
      a2 += w[4 * k4 + 2] * h4.z; a3 += w[4 * k4 + 3] * h4.w;
    }
    float acc = pv + (a0 + a1) + (a2 + a3);
    const int blk = tid >> 7;                // 0:i 1:f 2:g 3:o (torch order)
    gates[tid] = (blk == 2) ? tanhf(acc) : 1.f / (1.f + expf(-acc));
    __syncthreads();
    if (tid < H_) {
      float gi = gates[tid], gf = gates[tid + 128];
      float gg = gates[tid + 256], go = gates[tid + 384];
      float cn = gf * c + gi * gg;
      float hn = go * tanhf(cn);
      const int tc = dir ? (Tc - 1 - s) : s;
      bool  m  = (t0 + tc < len);
      float hold = h_hist[(s + SB - 1) & (SB - 1)][tid];
      c = m ? cn : c;
      h_hist[s & (SB - 1)][tid] = m ? hn : hold;
    }
    __syncthreads();
    if ((s & (SB - 1)) == (SB - 1)) {
      // flush the last 16 steps of h to hs (masked), all 512 threads.
      // stores overlap the next matvec; drained at the next barrier only.
      const int j  = tid & 127;
      const int g  = tid >> 7;
      const int s0 = s - (SB - 1);
#pragma unroll
      for (int qi = 0; qi < 4; ++qi) {
        const int q   = g + qi * 4;          // local slot 0..15
        const int ss  = s0 + q;
        const int tcq = dir ? (Tc - 1 - ss) : ss;
        const int tq  = t0 + tcq;
        const float v = (tq < len) ? h_hist[q][j] : 0.f;
        hs[(size_t)(b * T_ + tq) * 256 + dir * H_ + j] = v;
      }
    }
    pv = nv;
  }
  if (tid < H_) {
    sh[(dir * B_ + b) * H_ + tid] = h_hist[(Tc - 1) & (SB - 1)][tid];
    sc[(dir * B_ + b) * H_ + tid] = c;
  }
}

// ---------------------------------------------------------------------------
// Kernel 3: emissions em[m][k] = hs[m][:] . W_out[k][:] + b_out[k]
// ---------------------------------------------------------------------------
__global__ __launch_bounds__(256)
void emis_kernel(const float* __restrict__ hs, const float* __restrict__ Wout,
                 const float* __restrict__ bout, float* __restrict__ em)
{
  __shared__ __align__(16) float Wl[K_ * 256];
  const int tid = threadIdx.x;
  for (int i = tid; i < K_ * 256; i += 256) Wl[i] = Wout[i];
  __syncthreads();
  const int m = blockIdx.x * 256 + tid;
  const float* h = hs + (size_t)m * 256;
  float acc[K_] = {};
#pragma unroll 4
  for (int kk = 0; kk < 64; ++kk) {
    float4 h4 = *(const float4*)(h + kk * 4);
#pragma unroll
    for (int k9 = 0; k9 < K_; ++k9) {
      float4 w4 = *(const float4*)&Wl[k9 * 256 + kk * 4];
      acc[k9] += h4.x * w4.x + h4.y * w4.y + h4.z * w4.z + h4.w * w4.w;
    }
  }
#pragma unroll
  for (int k9 = 0; k9 < K_; ++k9) em[(size_t)m * K_ + k9] = acc[k9] + bout[k9];
}

// ---------------------------------------------------------------------------
// Kernel 4: Viterbi decode, one 64-lane wave per batch element.
// Lane k (<9) carries score[k]; shuffles broadcast the score vector.
// Backpointers as uint8 in LDS; padded positions written 0.
// ---------------------------------------------------------------------------
__global__ __launch_bounds__(64)
void viterbi_kernel(const float* __restrict__ em, const int* __restrict__ lengths,
                    const float* __restrict__ st, const float* __restrict__ en,
                    const float* __restrict__ trans, int* __restrict__ tags)
{
  const int b    = blockIdx.x;
  const int lane = threadIdx.x;
  __shared__ unsigned char hist[(T_ - 1) * 16];
  const int len = lengths[b];
  float tr[K_];
#pragma unroll
  for (int j = 0; j < K_; ++j) tr[j] = (lane < K_) ? trans[j * K_ + lane] : 0.f;
  float s = (lane < K_) ? st[lane] + em[(size_t)(b * T_) * K_ + lane] : -1e30f;
  for (int t = 1; t < len; ++t) {
    float best = -1e30f; int bj = 0;
#pragma unroll
    for (int j = 0; j < K_; ++j) {
      float v = __shfl(s, j) + tr[j];
      if (v > best) { best = v; bj = j; }    // strict > == first-max (argmax)
    }
    if (lane < K_) {
      s = best + em[(size_t)(b * T_ + t) * K_ + lane];
      hist[(t - 1) * 16 + lane] = (unsigned char)bj;
    }
  }
  float fs = (lane < K_) ? s + en[lane] : -1e30f;
  float best = -1e30f; int last = 0;
#pragma unroll
  for (int j = 0; j < K_; ++j) {
    float v = __shfl(fs, j);
    if (v > best) { best = v; last = j; }
  }
  __syncthreads();                            // hist visible to lane 0
  if (lane == 0) {
    int tag = last;
    tags[b * T_ + len - 1] = tag;
    for (int t = len - 2; t >= 0; --t) {
      tag = hist[t * 16 + tag];
      tags[b * T_ + t] = tag;
    }
  }
  for (int t = len + lane; t < T_; t += 64) tags[b * T_ + t] = 0;
}

// ---------------------------------------------------------------------------
extern "C" void kernel_launch(void* const* d_in, const int* in_sizes, int n_in,
                              void* d_out, int out_size, void* d_ws, size_t ws_size,
                              hipStream_t stream)
{
  const int*   sent  = (const int*)d_in[0];
  const int*   lens  = (const int*)d_in[1];
  const float* embed = (const float*)d_in[2];
  const float* Wif   = (const float*)d_in[3];
  const float* Whf   = (const float*)d_in[4];
  const float* bif   = (const float*)d_in[5];
  const float* bhf   = (const float*)d_in[6];
  const float* Wib   = (const float*)d_in[7];
  const float* Whb   = (const float*)d_in[8];
  const float* bib   = (const float*)d_in[9];
  const float* bhb   = (const float*)d_in[10];
  const float* Wout  = (const float*)d_in[11];
  const float* bout  = (const float*)d_in[12];
  const float* stt   = (const float*)d_in[13];
  const float* ent   = (const float*)d_in[14];
  const float* trans = (const float*)d_in[15];
  int* tags = (int*)d_out;

  // workspace layout (floats): hs | em | state_h | state_c | proj(chunked)
  float* ws   = (float*)d_ws;
  float* hs   = ws;                                  // B*T*256   (67.1 MB)
  float* em   = hs + (size_t)B_ * T_ * 256;          // B*T*9     ( 2.4 MB)
  float* sh   = em + (size_t)B_ * T_ * K_;           // 2*B*H carry h
  float* sc   = sh + (size_t)2 * B_ * H_;            // 2*B*H carry c
  float* proj = sc + (size_t)2 * B_ * H_;
  const size_t fixed_bytes = (size_t)(proj - ws) * sizeof(float);

  // largest time-chunk whose proj buffer fits the workspace (floor at 64)
  int Tc = 512;
  while (Tc > 64 && fixed_bytes + (size_t)B_ * Tc * 1024 * sizeof(float) > ws_size)
    Tc >>= 1;

  const int nch = T_ / Tc;
  for (int c2 = 0; c2 < nch; ++c2) {
    const int t0f = c2 * Tc;
    dim3 g1(16, B_ * (Tc >> 6));
    hipLaunchKernelGGL(proj_gemm, g1, dim3(256), 0, stream,
                       sent, embed, Wif, Wib, bif, bhf, bib, bhb, proj, t0f, Tc);
    dim3 g2(2, B_);
    hipLaunchKernelGGL(lstm_chunk, g2, dim3(512), 0, stream,
                       proj, Whf, Whb, lens, hs, sh, sc, t0f, Tc, (int)(c2 == 0));
  }
  hipLaunchKernelGGL(emis_kernel, dim3((B_ * T_) / 256), dim3(256), 0, stream,
                     hs, Wout, bout, em);
  hipLaunchKernelGGL(viterbi_kernel, dim3(B_), dim3(64), 0, stream,
                     em, lens, stt, ent, trans, tags);
}

// Round 7
// 940.733 us; speedup vs baseline: 3.0173x; 1.0553x over previous
//
#include <hip/hip_runtime.h>
#include <cmath>

#define B_  128
#define T_  512
#define E_  128
#define H_  128
#define G4  512   // 4*H
#define K_  9

// ---------------------------------------------------------------------------
// Kernel 1: input projection GEMM with fused embedding gather.
// proj[b][tc][n] = sum_k embed[sent[b,t]][k] * W_dir[n'][k] + (bih+bhh)[n']
// Tile: 64(M) x 64(N) x 128(K, full), 256 threads, 4x4 micro-tile.
// (R0 version — known ~195us/dispatch; R4/R5 rewrites both regressed.)
// ---------------------------------------------------------------------------
__global__ __launch_bounds__(256, 2)
void proj_gemm(const int* __restrict__ sent, const float* __restrict__ embed,
               const float* __restrict__ Wf, const float* __restrict__ Wb,
               const float* __restrict__ bif, const float* __restrict__ bhf,
               const float* __restrict__ bib, const float* __restrict__ bhb,
               float* __restrict__ proj, int t0f, int Tc)
{
  __shared__ __align__(16) float Al[128 * 64];  // [k][m]
  __shared__ __align__(16) float Bl[128 * 64];  // [k][n]
  const int tid   = threadIdx.x;
  const int ntile = blockIdx.x;            // 0..15
  const int mtile = blockIdx.y;
  const int tpb   = Tc >> 6;               // 64-row tiles per batch element
  const int b     = mtile / tpb;
  const int toff  = (mtile - b * tpb) << 6;
  const int dir   = ntile >> 3;
  const int t0    = dir ? (T_ - t0f - Tc) : t0f;
  const float* __restrict__ W = dir ? Wb : Wf;
  const int n0 = (ntile & 7) << 6;         // row offset inside W (0..448)

  {
    const int r  = tid & 63;
    const int kc = tid >> 6;               // 0..3, each covers 32 k's
    const int t  = t0 + toff + r;
    const int vid = sent[b * T_ + t];
    const float* arow = embed + (size_t)vid * E_ + kc * 32;
    const float* brow = W + (size_t)(n0 + r) * E_ + kc * 32;
#pragma unroll
    for (int q = 0; q < 8; ++q) {
      float4 av = *(const float4*)(arow + q * 4);
      float4 bv = *(const float4*)(brow + q * 4);
      int k0 = kc * 32 + q * 4;
      Al[(k0 + 0) * 64 + r] = av.x; Al[(k0 + 1) * 64 + r] = av.y;
      Al[(k0 + 2) * 64 + r] = av.z; Al[(k0 + 3) * 64 + r] = av.w;
      Bl[(k0 + 0) * 64 + r] = bv.x; Bl[(k0 + 1) * 64 + r] = bv.y;
      Bl[(k0 + 2) * 64 + r] = bv.z; Bl[(k0 + 3) * 64 + r] = bv.w;
    }
  }
  __syncthreads();

  const int mg = tid & 15, ng = tid >> 4;
  float acc[4][4] = {};
#pragma unroll 8
  for (int k = 0; k < 128; ++k) {
    float4 a  = *(const float4*)&Al[k * 64 + mg * 4];
    float4 bb = *(const float4*)&Bl[k * 64 + ng * 4];
    acc[0][0] += a.x * bb.x; acc[0][1] += a.x * bb.y; acc[0][2] += a.x * bb.z; acc[0][3] += a.x * bb.w;
    acc[1][0] += a.y * bb.x; acc[1][1] += a.y * bb.y; acc[1][2] += a.y * bb.z; acc[1][3] += a.y * bb.w;
    acc[2][0] += a.z * bb.x; acc[2][1] += a.z * bb.y; acc[2][2] += a.z * bb.z; acc[2][3] += a.z * bb.w;
    acc[3][0] += a.w * bb.x; acc[3][1] += a.w * bb.y; acc[3][2] += a.w * bb.z; acc[3][3] += a.w * bb.w;
  }

  const float* bi = dir ? bib : bif;
  const float* bh = dir ? bhb : bhf;
  const int nl = ng * 4;
  float4 bias;
  bias.x = bi[n0 + nl + 0] + bh[n0 + nl + 0];
  bias.y = bi[n0 + nl + 1] + bh[n0 + nl + 1];
  bias.z = bi[n0 + nl + 2] + bh[n0 + nl + 2];
  bias.w = bi[n0 + nl + 3] + bh[n0 + nl + 3];
#pragma unroll
  for (int i = 0; i < 4; ++i) {
    const int tloc = toff + mg * 4 + i;
    float4 o;
    o.x = acc[i][0] + bias.x; o.y = acc[i][1] + bias.y;
    o.z = acc[i][2] + bias.z; o.w = acc[i][3] + bias.w;
    *(float4*)&proj[((size_t)(b * Tc + tloc)) * 1024 + dir * G4 + n0 + nl] = o;
  }
}

// ---------------------------------------------------------------------------
// Kernel 2: LSTM recurrence — R7 restructure for DS-pipe pressure.
//   Diagnosis (R2/R6 counters): 8 waves x 32 broadcast ds_read_b128 = 256
//   DS instrs/step x 8cyc (1KB through the 128B/clk LDS port each) = 2048
//   cyc/step -> DS-BW bound; VALU (54%) runs underneath.
//   New layout (512 thr, 8 waves): lane l of wave w:
//     unit u = w*16 + (l&15); gp=(l>>4)&1 (0:i,f  1:g,o); kh=l>>5 (k half).
//   Each thread: 2 rows x 64 k -> one h4 read feeds 2 rows: 16 ds_read
//   per thread = 128 DS instr/step (HALF). k-halves summed via
//   __shfl_xor(32); gate exchange via __shfl_xor(16) -- all 4 gates of a
//   unit live in one wave, so the gates[] LDS buffer and one of the two
//   barriers are gone (ONE barrier/step, h_hist double-buffered).
//   Cell update duplicated in the 4 lanes of a unit (identical FP ops).
// Packed-sequence semantics: state frozen + output zeroed where t >= len.
// ---------------------------------------------------------------------------
__global__ __launch_bounds__(512, 2)
void lstm_chunk(const float* __restrict__ proj,
                const float* __restrict__ Whf, const float* __restrict__ Whb,
                const int* __restrict__ lengths,
                float* __restrict__ hs,
                float* __restrict__ sh, float* __restrict__ sc,
                int t0f, int Tc, int first)
{
  const int dir = blockIdx.x;
  const int b   = blockIdx.y;
  const int tid = threadIdx.x;
  const int l   = tid & 63;
  const int wv  = tid >> 6;
  const int u   = wv * 16 + (l & 15);      // hidden unit 0..127
  const int gp  = (l >> 4) & 1;            // 0: gates i,f   1: gates g,o
  const int kh  = l >> 5;                  // k half 0/1
  const int rowA = u + (gp ? 256 : 0);     // i or g
  const int rowB = rowA + 128;             // f or o
  const float* __restrict__ Whh = dir ? Whb : Whf;
  __shared__ __align__(16) float h_hist[2][H_];

  float wA[64], wB[64];
  {
    const float* wra = Whh + (size_t)rowA * H_ + kh * 64;
    const float* wrb = Whh + (size_t)rowB * H_ + kh * 64;
#pragma unroll
    for (int k = 0; k < 64; k += 4) {
      float4 va = *(const float4*)(wra + k);
      float4 vb = *(const float4*)(wrb + k);
      wA[k] = va.x; wA[k + 1] = va.y; wA[k + 2] = va.z; wA[k + 3] = va.w;
      wB[k] = vb.x; wB[k + 1] = vb.y; wB[k + 2] = vb.z; wB[k + 3] = vb.w;
    }
  }
#pragma unroll
  for (int k = 0; k < 64; ++k) {
    asm volatile("" : "+v"(wA[k]));
    asm volatile("" : "+v"(wB[k]));
  }

  const int len = lengths[b];
  const int t0  = dir ? (T_ - t0f - Tc) : t0f;
  float c = 0.f, h_reg = 0.f;
  if (!first) {
    c     = sc[(dir * B_ + b) * H_ + u];
    h_reg = sh[(dir * B_ + b) * H_ + u];
  }
  if (l < 16) h_hist[1][u] = h_reg;        // slot read by step 0
  __syncthreads();

  const float* projpA = proj + (size_t)b * Tc * 1024 + dir * G4 + rowA;
  const float* projpB = projpA + 128;
  const int tc00 = dir ? (Tc - 1) : 0;
  float pvA = projpA[(size_t)tc00 * 1024];
  float pvB = projpB[(size_t)tc00 * 1024];

  for (int s = 0; s < Tc; ++s) {
    const int tc = dir ? (Tc - 1 - s) : s;
    const int t  = t0 + tc;
    float nvA = 0.f, nvB = 0.f;
    if (s + 1 < Tc) {
      const int tcn = dir ? (Tc - 2 - s) : (s + 1);
      nvA = projpA[(size_t)tcn * 1024];
      nvB = projpB[(size_t)tcn * 1024];
    }
    const float* hp = h_hist[(s + 1) & 1] + kh * 64;   // h_{s-1}, own k-half
    float a0 = 0.f, a1 = 0.f, a2 = 0.f, a3 = 0.f;
#pragma unroll
    for (int k4 = 0; k4 < 16; ++k4) {
      float4 h4 = *(const float4*)&hp[k4 * 4];
      a0 += wA[4 * k4 + 0] * h4.x; a1 += wA[4 * k4 + 1] * h4.y;
      a0 += wA[4 * k4 + 2] * h4.z; a1 += wA[4 * k4 + 3] * h4.w;
      a2 += wB[4 * k4 + 0] * h4.x; a3 += wB[4 * k4 + 1] * h4.y;
      a2 += wB[4 * k4 + 2] * h4.z; a3 += wB[4 * k4 + 3] * h4.w;
    }
    float sA = a0 + a1; sA += __shfl_xor(sA, 32); sA += pvA;
    float sB = a2 + a3; sB += __shfl_xor(sB, 32); sB += pvB;
    const float gA = gp ? tanhf(sA) : 1.f / (1.f + expf(-sA));
    const float gB = 1.f / (1.f + expf(-sB));
    const float xA = __shfl_xor(gA, 16);
    const float xB = __shfl_xor(gB, 16);
    const float gi = gp ? xA : gA;
    const float gf = gp ? xB : gB;
    const float gg = gp ? gA : xA;
    const float go = gp ? gB : xB;
    const float cn = gf * c + gi * gg;
    const float hn = go * tanhf(cn);
    const bool  m  = (t < len);
    c     = m ? cn : c;
    h_reg = m ? hn : h_reg;
    if (l < 16) {
      h_hist[s & 1][u] = h_reg;
      hs[(size_t)(b * T_ + t) * 256 + dir * H_ + u] = m ? hn : 0.f;
    }
    __syncthreads();
    pvA = nvA; pvB = nvB;
  }
  if (l < 16 && wv == (u >> 4)) {          // one writer per unit
    sh[(dir * B_ + b) * H_ + u] = h_reg;
    sc[(dir * B_ + b) * H_ + u] = c;
  }
}

// ---------------------------------------------------------------------------
// Kernel 3: emissions em[m][k] = hs[m][:] . W_out[k][:] + b_out[k]
// ---------------------------------------------------------------------------
__global__ __launch_bounds__(256)
void emis_kernel(const float* __restrict__ hs, const float* __restrict__ Wout,
                 const float* __restrict__ bout, float* __restrict__ em)
{
  __shared__ __align__(16) float Wl[K_ * 256];
  const int tid = threadIdx.x;
  for (int i = tid; i < K_ * 256; i += 256) Wl[i] = Wout[i];
  __syncthreads();
  const int m = blockIdx.x * 256 + tid;
  const float* h = hs + (size_t)m * 256;
  float acc[K_] = {};
#pragma unroll 4
  for (int kk = 0; kk < 64; ++kk) {
    float4 h4 = *(const float4*)(h + kk * 4);
#pragma unroll
    for (int k9 = 0; k9 < K_; ++k9) {
      float4 w4 = *(const float4*)&Wl[k9 * 256 + kk * 4];
      acc[k9] += h4.x * w4.x + h4.y * w4.y + h4.z * w4.z + h4.w * w4.w;
    }
  }
#pragma unroll
  for (int k9 = 0; k9 < K_; ++k9) em[(size_t)m * K_ + k9] = acc[k9] + bout[k9];
}

// ---------------------------------------------------------------------------
// Kernel 4: Viterbi decode, one 64-lane wave per batch element.
// ---------------------------------------------------------------------------
__global__ __launch_bounds__(64)
void viterbi_kernel(const float* __restrict__ em, const int* __restrict__ lengths,
                    const float* __restrict__ st, const float* __restrict__ en,
                    const float* __restrict__ trans, int* __restrict__ tags)
{
  const int b    = blockIdx.x;
  const int lane = threadIdx.x;
  __shared__ unsigned char hist[(T_ - 1) * 16];
  const int len = lengths[b];
  float tr[K_];
#pragma unroll
  for (int j = 0; j < K_; ++j) tr[j] = (lane < K_) ? trans[j * K_ + lane] : 0.f;
  float s = (lane < K_) ? st[lane] + em[(size_t)(b * T_) * K_ + lane] : -1e30f;
  for (int t = 1; t < len; ++t) {
    float best = -1e30f; int bj = 0;
#pragma unroll
    for (int j = 0; j < K_; ++j) {
      float v = __shfl(s, j) + tr[j];
      if (v > best) { best = v; bj = j; }    // strict > == first-max (argmax)
    }
    if (lane < K_) {
      s = best + em[(size_t)(b * T_ + t) * K_ + lane];
      hist[(t - 1) * 16 + lane] = (unsigned char)bj;
    }
  }
  float fs = (lane < K_) ? s + en[lane] : -1e30f;
  float best = -1e30f; int last = 0;
#pragma unroll
  for (int j = 0; j < K_; ++j) {
    float v = __shfl(fs, j);
    if (v > best) { best = v; last = j; }
  }
  __syncthreads();                            // hist visible to lane 0
  if (lane == 0) {
    int tag = last;
    tags[b * T_ + len - 1] = tag;
    for (int t = len - 2; t >= 0; --t) {
      tag = hist[t * 16 + tag];
      tags[b * T_ + t] = tag;
    }
  }
  for (int t = len + lane; t < T_; t += 64) tags[b * T_ + t] = 0;
}

// ---------------------------------------------------------------------------
extern "C" void kernel_launch(void* const* d_in, const int* in_sizes, int n_in,
                              void* d_out, int out_size, void* d_ws, size_t ws_size,
                              hipStream_t stream)
{
  const int*   sent  = (const int*)d_in[0];
  const int*   lens  = (const int*)d_in[1];
  const float* embed = (const float*)d_in[2];
  const float* Wif   = (const float*)d_in[3];
  const float* Whf   = (const float*)d_in[4];
  const float* bif   = (const float*)d_in[5];
  const float* bhf   = (const float*)d_in[6];
  const float* Wib   = (const float*)d_in[7];
  const float* Whb   = (const float*)d_in[8];
  const float* bib   = (const float*)d_in[9];
  const float* bhb   = (const float*)d_in[10];
  const float* Wout  = (const float*)d_in[11];
  const float* bout  = (const float*)d_in[12];
  const float* stt   = (const float*)d_in[13];
  const float* ent   = (const float*)d_in[14];
  const float* trans = (const float*)d_in[15];
  int* tags = (int*)d_out;

  // workspace layout (floats): hs | em | state_h | state_c | proj(chunked)
  float* ws   = (float*)d_ws;
  float* hs   = ws;                                  // B*T*256   (67.1 MB)
  float* em   = hs + (size_t)B_ * T_ * 256;          // B*T*9     ( 2.4 MB)
  float* sh   = em + (size_t)B_ * T_ * K_;           // 2*B*H carry h
  float* sc   = sh + (size_t)2 * B_ * H_;            // 2*B*H carry c
  float* proj = sc + (size_t)2 * B_ * H_;
  const size_t fixed_bytes = (size_t)(proj - ws) * sizeof(float);

  // largest time-chunk whose proj buffer fits the workspace (floor at 64)
  int Tc = 512;
  while (Tc > 64 && fixed_bytes + (size_t)B_ * Tc * 1024 * sizeof(float) > ws_size)
    Tc >>= 1;

  const int nch = T_ / Tc;
  for (int c2 = 0; c2 < nch; ++c2) {
    const int t0f = c2 * Tc;
    dim3 g1(16, B_ * (Tc >> 6));
    hipLaunchKernelGGL(proj_gemm, g1, dim3(256), 0, stream,
                       sent, embed, Wif, Wib, bif, bhf, bib, bhb, proj, t0f, Tc);
    dim3 g2(2, B_);
    hipLaunchKernelGGL(lstm_chunk, g2, dim3(512), 0, stream,
                       proj, Whf, Whb, lens, hs, sh, sc, t0f, Tc, (int)(c2 == 0));
  }
  hipLaunchKernelGGL(emis_kernel, dim3((B_ * T_) / 256), dim3(256), 0, stream,
                     hs, Wout, bout, em);
  hipLaunchKernelGGL(viterbi_kernel, dim3(B_), dim3(64), 0, stream,
                     em, lens, stt, ent, trans, tags);
}

// Round 8
// 837.891 us; speedup vs baseline: 3.3876x; 1.1227x over previous
//
#include <hip/hip_runtime.h>
#include <cmath>

#define B_  128
#define T_  512
#define E_  128
#define H_  128
#define G4  512   // 4*H
#define K_  9

// ---------------------------------------------------------------------------
// Kernel 1: input projection GEMM with fused embedding gather.
// proj[b][tc][n] = sum_k embed[sent[b,t]][k] * W_dir[n'][k] + (bih+bhh)[n']
// Tile: 64(M) x 64(N) x 128(K, full), 256 threads, 4x4 micro-tile.
// (R0 version — known ~195us/dispatch; R4/R5 rewrites both regressed.)
// ---------------------------------------------------------------------------
__global__ __launch_bounds__(256, 2)
void proj_gemm(const int* __restrict__ sent, const float* __restrict__ embed,
               const float* __restrict__ Wf, const float* __restrict__ Wb,
               const float* __restrict__ bif, const float* __restrict__ bhf,
               const float* __restrict__ bib, const float* __restrict__ bhb,
               float* __restrict__ proj, int t0f, int Tc)
{
  __shared__ __align__(16) float Al[128 * 64];  // [k][m]
  __shared__ __align__(16) float Bl[128 * 64];  // [k][n]
  const int tid   = threadIdx.x;
  const int ntile = blockIdx.x;            // 0..15
  const int mtile = blockIdx.y;
  const int tpb   = Tc >> 6;               // 64-row tiles per batch element
  const int b     = mtile / tpb;
  const int toff  = (mtile - b * tpb) << 6;
  const int dir   = ntile >> 3;
  const int t0    = dir ? (T_ - t0f - Tc) : t0f;
  const float* __restrict__ W = dir ? Wb : Wf;
  const int n0 = (ntile & 7) << 6;         // row offset inside W (0..448)

  {
    const int r  = tid & 63;
    const int kc = tid >> 6;               // 0..3, each covers 32 k's
    const int t  = t0 + toff + r;
    const int vid = sent[b * T_ + t];
    const float* arow = embed + (size_t)vid * E_ + kc * 32;
    const float* brow = W + (size_t)(n0 + r) * E_ + kc * 32;
#pragma unroll
    for (int q = 0; q < 8; ++q) {
      float4 av = *(const float4*)(arow + q * 4);
      float4 bv = *(const float4*)(brow + q * 4);
      int k0 = kc * 32 + q * 4;
      Al[(k0 + 0) * 64 + r] = av.x; Al[(k0 + 1) * 64 + r] = av.y;
      Al[(k0 + 2) * 64 + r] = av.z; Al[(k0 + 3) * 64 + r] = av.w;
      Bl[(k0 + 0) * 64 + r] = bv.x; Bl[(k0 + 1) * 64 + r] = bv.y;
      Bl[(k0 + 2) * 64 + r] = bv.z; Bl[(k0 + 3) * 64 + r] = bv.w;
    }
  }
  __syncthreads();

  const int mg = tid & 15, ng = tid >> 4;
  float acc[4][4] = {};
#pragma unroll 8
  for (int k = 0; k < 128; ++k) {
    float4 a  = *(const float4*)&Al[k * 64 + mg * 4];
    float4 bb = *(const float4*)&Bl[k * 64 + ng * 4];
    acc[0][0] += a.x * bb.x; acc[0][1] += a.x * bb.y; acc[0][2] += a.x * bb.z; acc[0][3] += a.x * bb.w;
    acc[1][0] += a.y * bb.x; acc[1][1] += a.y * bb.y; acc[1][2] += a.y * bb.z; acc[1][3] += a.y * bb.w;
    acc[2][0] += a.z * bb.x; acc[2][1] += a.z * bb.y; acc[2][2] += a.z * bb.z; acc[2][3] += a.z * bb.w;
    acc[3][0] += a.w * bb.x; acc[3][1] += a.w * bb.y; acc[3][2] += a.w * bb.z; acc[3][3] += a.w * bb.w;
  }

  const float* bi = dir ? bib : bif;
  const float* bh = dir ? bhb : bhf;
  const int nl = ng * 4;
  float4 bias;
  bias.x = bi[n0 + nl + 0] + bh[n0 + nl + 0];
  bias.y = bi[n0 + nl + 1] + bh[n0 + nl + 1];
  bias.z = bi[n0 + nl + 2] + bh[n0 + nl + 2];
  bias.w = bi[n0 + nl + 3] + bh[n0 + nl + 3];
#pragma unroll
  for (int i = 0; i < 4; ++i) {
    const int tloc = toff + mg * 4 + i;
    float4 o;
    o.x = acc[i][0] + bias.x; o.y = acc[i][1] + bias.y;
    o.z = acc[i][2] + bias.z; o.w = acc[i][3] + bias.w;
    *(float4*)&proj[((size_t)(b * Tc + tloc)) * 1024 + dir * G4 + n0 + nl] = o;
  }
}

// ---------------------------------------------------------------------------
// Fast, branchless nonlinearities (v_exp_f32 + v_rcp_f32).
//   sigmoid(x) = rcp(1+exp(-x));  tanh(x) = 2*rcp(1+exp(-2x)) - 1.
//   Unified gate: kf=1+gp -> kf*rcp(1+exp(-kf*x)) - gp  (gp=0: sigmoid,
//   gp=1: tanh) — removes the divergent libm tanhf/expf paths that R7's
//   counters showed dominating VALU (77% busy, ~3/4 of it non-matvec).
// ---------------------------------------------------------------------------
__device__ __forceinline__ float fast_rcp(float x) {
  return __builtin_amdgcn_rcpf(x);
}
__device__ __forceinline__ float fast_sig(float x) {
  return fast_rcp(1.f + __expf(-x));
}
__device__ __forceinline__ float fast_tanh(float x) {
  return 2.f * fast_rcp(1.f + __expf(-2.f * x)) - 1.f;
}

// ---------------------------------------------------------------------------
// Kernel 2: LSTM recurrence (R7 structure + R8 fast gates).
//   512 thr, 8 waves: lane l of wave w: unit u=w*16+(l&15); gp=(l>>4)&1
//   (0:i,f  1:g,o); kh=l>>5 (k half). 2 rows x 64 k per thread; k-halves
//   summed via __shfl_xor(32); gate exchange via __shfl_xor(16); one
//   barrier/step; h_hist double-buffered.
// Packed-sequence semantics: state frozen + output zeroed where t >= len.
// ---------------------------------------------------------------------------
__global__ __launch_bounds__(512, 2)
void lstm_chunk(const float* __restrict__ proj,
                const float* __restrict__ Whf, const float* __restrict__ Whb,
                const int* __restrict__ lengths,
                float* __restrict__ hs,
                float* __restrict__ sh, float* __restrict__ sc,
                int t0f, int Tc, int first)
{
  const int dir = blockIdx.x;
  const int b   = blockIdx.y;
  const int tid = threadIdx.x;
  const int l   = tid & 63;
  const int wv  = tid >> 6;
  const int u   = wv * 16 + (l & 15);      // hidden unit 0..127
  const int gp  = (l >> 4) & 1;            // 0: gates i,f   1: gates g,o
  const int kh  = l >> 5;                  // k half 0/1
  const int rowA = u + (gp ? 256 : 0);     // i or g
  const int rowB = rowA + 128;             // f or o
  const float* __restrict__ Whh = dir ? Whb : Whf;
  __shared__ __align__(16) float h_hist[2][H_];

  float wA[64], wB[64];
  {
    const float* wra = Whh + (size_t)rowA * H_ + kh * 64;
    const float* wrb = Whh + (size_t)rowB * H_ + kh * 64;
#pragma unroll
    for (int k = 0; k < 64; k += 4) {
      float4 va = *(const float4*)(wra + k);
      float4 vb = *(const float4*)(wrb + k);
      wA[k] = va.x; wA[k + 1] = va.y; wA[k + 2] = va.z; wA[k + 3] = va.w;
      wB[k] = vb.x; wB[k + 1] = vb.y; wB[k + 2] = vb.z; wB[k + 3] = vb.w;
    }
  }
#pragma unroll
  for (int k = 0; k < 64; ++k) {
    asm volatile("" : "+v"(wA[k]));
    asm volatile("" : "+v"(wB[k]));
  }

  const int len = lengths[b];
  const int t0  = dir ? (T_ - t0f - Tc) : t0f;
  const float fgp = (float)gp;
  const float kf  = 1.f + fgp;             // 1: sigmoid  2: tanh scaling
  float c = 0.f, h_reg = 0.f;
  if (!first) {
    c     = sc[(dir * B_ + b) * H_ + u];
    h_reg = sh[(dir * B_ + b) * H_ + u];
  }
  if (l < 16) h_hist[1][u] = h_reg;        // slot read by step 0
  __syncthreads();

  const float* projpA = proj + (size_t)b * Tc * 1024 + dir * G4 + rowA;
  const float* projpB = projpA + 128;
  const int tc00 = dir ? (Tc - 1) : 0;
  float pvA = projpA[(size_t)tc00 * 1024];
  float pvB = projpB[(size_t)tc00 * 1024];

  for (int s = 0; s < Tc; ++s) {
    const int tc = dir ? (Tc - 1 - s) : s;
    const int t  = t0 + tc;
    float nvA = 0.f, nvB = 0.f;
    if (s + 1 < Tc) {
      const int tcn = dir ? (Tc - 2 - s) : (s + 1);
      nvA = projpA[(size_t)tcn * 1024];
      nvB = projpB[(size_t)tcn * 1024];
    }
    const float* hp = h_hist[(s + 1) & 1] + kh * 64;   // h_{s-1}, own k-half
    float a0 = 0.f, a1 = 0.f, a2 = 0.f, a3 = 0.f;
#pragma unroll
    for (int k4 = 0; k4 < 16; ++k4) {
      float4 h4 = *(const float4*)&hp[k4 * 4];
      a0 += wA[4 * k4 + 0] * h4.x; a1 += wA[4 * k4 + 1] * h4.y;
      a0 += wA[4 * k4 + 2] * h4.z; a1 += wA[4 * k4 + 3] * h4.w;
      a2 += wB[4 * k4 + 0] * h4.x; a3 += wB[4 * k4 + 1] * h4.y;
      a2 += wB[4 * k4 + 2] * h4.z; a3 += wB[4 * k4 + 3] * h4.w;
    }
    float sA = a0 + a1; sA += __shfl_xor(sA, 32); sA += pvA;
    float sB = a2 + a3; sB += __shfl_xor(sB, 32); sB += pvB;
    // gA: sigmoid (gp=0) or tanh (gp=1), branchless; gB: always sigmoid.
    const float gA = kf * fast_rcp(1.f + __expf(-kf * sA)) - fgp;
    const float gB = fast_sig(sB);
    const float xA = __shfl_xor(gA, 16);
    const float xB = __shfl_xor(gB, 16);
    const float gi = gp ? xA : gA;
    const float gf = gp ? xB : gB;
    const float gg = gp ? gA : xA;
    const float go = gp ? gB : xB;
    const float cn = gf * c + gi * gg;
    const float hn = go * fast_tanh(cn);
    const bool  m  = (t < len);
    c     = m ? cn : c;
    h_reg = m ? hn : h_reg;
    if (l < 16) {
      h_hist[s & 1][u] = h_reg;
      hs[(size_t)(b * T_ + t) * 256 + dir * H_ + u] = m ? hn : 0.f;
    }
    __syncthreads();
    pvA = nvA; pvB = nvB;
  }
  if (l < 16 && wv == (u >> 4)) {          // one writer per unit
    sh[(dir * B_ + b) * H_ + u] = h_reg;
    sc[(dir * B_ + b) * H_ + u] = c;
  }
}

// ---------------------------------------------------------------------------
// Kernel 3: emissions em[m][k] = hs[m][:] . W_out[k][:] + b_out[k]
// ---------------------------------------------------------------------------
__global__ __launch_bounds__(256)
void emis_kernel(const float* __restrict__ hs, const float* __restrict__ Wout,
                 const float* __restrict__ bout, float* __restrict__ em)
{
  __shared__ __align__(16) float Wl[K_ * 256];
  const int tid = threadIdx.x;
  for (int i = tid; i < K_ * 256; i += 256) Wl[i] = Wout[i];
  __syncthreads();
  const int m = blockIdx.x * 256 + tid;
  const float* h = hs + (size_t)m * 256;
  float acc[K_] = {};
#pragma unroll 4
  for (int kk = 0; kk < 64; ++kk) {
    float4 h4 = *(const float4*)(h + kk * 4);
#pragma unroll
    for (int k9 = 0; k9 < K_; ++k9) {
      float4 w4 = *(const float4*)&Wl[k9 * 256 + kk * 4];
      acc[k9] += h4.x * w4.x + h4.y * w4.y + h4.z * w4.z + h4.w * w4.w;
    }
  }
#pragma unroll
  for (int k9 = 0; k9 < K_; ++k9) em[(size_t)m * K_ + k9] = acc[k9] + bout[k9];
}

// ---------------------------------------------------------------------------
// Kernel 4: Viterbi decode, one 64-lane wave per batch element.
// ---------------------------------------------------------------------------
__global__ __launch_bounds__(64)
void viterbi_kernel(const float* __restrict__ em, const int* __restrict__ lengths,
                    const float* __restrict__ st, const float* __restrict__ en,
                    const float* __restrict__ trans, int* __restrict__ tags)
{
  const int b    = blockIdx.x;
  const int lane = threadIdx.x;
  __shared__ unsigned char hist[(T_ - 1) * 16];
  const int len = lengths[b];
  float tr[K_];
#pragma unroll
  for (int j = 0; j < K_; ++j) tr[j] = (lane < K_) ? trans[j * K_ + lane] : 0.f;
  float s = (lane < K_) ? st[lane] + em[(size_t)(b * T_) * K_ + lane] : -1e30f;
  for (int t = 1; t < len; ++t) {
    float best = -1e30f; int bj = 0;
#pragma unroll
    for (int j = 0; j < K_; ++j) {
      float v = __shfl(s, j) + tr[j];
      if (v > best) { best = v; bj = j; }    // strict > == first-max (argmax)
    }
    if (lane < K_) {
      s = best + em[(size_t)(b * T_ + t) * K_ + lane];
      hist[(t - 1) * 16 + lane] = (unsigned char)bj;
    }
  }
  float fs = (lane < K_) ? s + en[lane] : -1e30f;
  float best = -1e30f; int last = 0;
#pragma unroll
  for (int j = 0; j < K_; ++j) {
    float v = __shfl(fs, j);
    if (v > best) { best = v; last = j; }
  }
  __syncthreads();                            // hist visible to lane 0
  if (lane == 0) {
    int tag = last;
    tags[b * T_ + len - 1] = tag;
    for (int t = len - 2; t >= 0; --t) {
      tag = hist[t * 16 + tag];
      tags[b * T_ + t] = tag;
    }
  }
  for (int t = len + lane; t < T_; t += 64) tags[b * T_ + t] = 0;
}

// ---------------------------------------------------------------------------
extern "C" void kernel_launch(void* const* d_in, const int* in_sizes, int n_in,
                              void* d_out, int out_size, void* d_ws, size_t ws_size,
                              hipStream_t stream)
{
  const int*   sent  = (const int*)d_in[0];
  const int*   lens  = (const int*)d_in[1];
  const float* embed = (const float*)d_in[2];
  const float* Wif   = (const float*)d_in[3];
  const float* Whf   = (const float*)d_in[4];
  const float* bif   = (const float*)d_in[5];
  const float* bhf   = (const float*)d_in[6];
  const float* Wib   = (const float*)d_in[7];
  const float* Whb   = (const float*)d_in[8];
  const float* bib   = (const float*)d_in[9];
  const float* bhb   = (const float*)d_in[10];
  const float* Wout  = (const float*)d_in[11];
  const float* bout  = (const float*)d_in[12];
  const float* stt   = (const float*)d_in[13];
  const float* ent   = (const float*)d_in[14];
  const float* trans = (const float*)d_in[15];
  int* tags = (int*)d_out;

  // workspace layout (floats): hs | em | state_h | state_c | proj(chunked)
  float* ws   = (float*)d_ws;
  float* hs   = ws;                                  // B*T*256   (67.1 MB)
  float* em   = hs + (size_t)B_ * T_ * 256;          // B*T*9     ( 2.4 MB)
  float* sh   = em + (size_t)B_ * T_ * K_;           // 2*B*H carry h
  float* sc   = sh + (size_t)2 * B_ * H_;            // 2*B*H carry c
  float* proj = sc + (size_t)2 * B_ * H_;
  const size_t fixed_bytes = (size_t)(proj - ws) * sizeof(float);

  // largest time-chunk whose proj buffer fits the workspace (floor at 64)
  int Tc = 512;
  while (Tc > 64 && fixed_bytes + (size_t)B_ * Tc * 1024 * sizeof(float) > ws_size)
    Tc >>= 1;

  const int nch = T_ / Tc;
  for (int c2 = 0; c2 < nch; ++c2) {
    const int t0f = c2 * Tc;
    dim3 g1(16, B_ * (Tc >> 6));
    hipLaunchKernelGGL(proj_gemm, g1, dim3(256), 0, stream,
                       sent, embed, Wif, Wib, bif, bhf, bib, bhb, proj, t0f, Tc);
    dim3 g2(2, B_);
    hipLaunchKernelGGL(lstm_chunk, g2, dim3(512), 0, stream,
                       proj, Whf, Whb, lens, hs, sh, sc, t0f, Tc, (int)(c2 == 0));
  }
  hipLaunchKernelGGL(emis_kernel, dim3((B_ * T_) / 256), dim3(256), 0, stream,
                     hs, Wout, bout, em);
  hipLaunchKernelGGL(viterbi_kernel, dim3(B_), dim3(64), 0, stream,
                     em, lens, stt, ent, trans, tags);
}